// Round 2
// baseline (197.458 us; speedup 1.0000x reference)
//
#include <hip/hip_runtime.h>

#define NPOS 8192
#define NNEG 40960
#define NEDGE (NPOS + NNEG)
#define DIM 128
#define MARGIN 0.1f

// acc[0] = A (sum |n_j - (p_i - M)|), acc[1] = sum pos_sim, acc[2] = sum neg_sim

// -------- kernel 1: one wave (64 lanes) per edge, dot product of two rows ----
// Each 256-thread block = 4 consecutive waves; NPOS % 4 == 0 so every block is
// purely-pos or purely-neg -> one atomicAdd per block into Sp or Sn.
__global__ __launch_bounds__(256) void sims_kernel(
    const float* __restrict__ emb,
    const int* __restrict__ pos_idx,
    const int* __restrict__ neg_idx,
    float* __restrict__ sims, float* __restrict__ acc) {
  const int tid = threadIdx.x;
  const int wave = blockIdx.x * 4 + (tid >> 6);
  const int lane = tid & 63;
  int s, d;
  if (wave < NPOS) {
    s = pos_idx[wave];
    d = pos_idx[NPOS + wave];
  } else {
    const int e = wave - NPOS;
    s = neg_idx[e];
    d = neg_idx[NNEG + e];
  }
  const float2 a = *(const float2*)(emb + (long long)s * DIM + lane * 2);
  const float2 b = *(const float2*)(emb + (long long)d * DIM + lane * 2);
  float v = a.x * b.x + a.y * b.y;
#pragma unroll
  for (int m = 32; m >= 1; m >>= 1) v += __shfl_xor(v, m, 64);
  __shared__ float wv[4];
  if (lane == 0) {
    sims[wave] = v;
    wv[tid >> 6] = v;
  }
  __syncthreads();
  if (tid == 0) {
    const float bs = (wv[0] + wv[1]) + (wv[2] + wv[3]);
    atomicAdd(acc + (blockIdx.x < (NPOS / 4) ? 1 : 2), bs);
  }
}

// -------- kernel 2: A = sum_{i,j} |n_j - (p_i - MARGIN)|  --------------------
// grid = 8 pos-chunks (1024 each) x 80 neg-segments (512 each) = 640 blocks
#define POSC 1024
#define NEGSEG 512

__global__ __launch_bounds__(256) void pair_kernel(
    const float* __restrict__ sims, float* __restrict__ acc) {
  __shared__ float sneg[NEGSEG];
  const float* pos = sims;
  const float* neg = sims + NPOS;
  const int pc = blockIdx.x & 7;   // pos chunk
  const int ns = blockIdx.x >> 3;  // neg segment
  const int tid = threadIdx.x;

  for (int t = tid; t < NEGSEG; t += 256) sneg[t] = neg[ns * NEGSEG + t];

  const int pb = pc * POSC + tid;
  const float q0 = pos[pb]       - MARGIN;
  const float q1 = pos[pb + 256] - MARGIN;
  const float q2 = pos[pb + 512] - MARGIN;
  const float q3 = pos[pb + 768] - MARGIN;
  __syncthreads();

  float a0 = 0.f, a1 = 0.f, a2 = 0.f, a3 = 0.f;
#pragma unroll 4
  for (int j = 0; j < NEGSEG; j += 4) {
    const float4 n = *(const float4*)(sneg + j);
    a0 += fabsf(n.x - q0); a1 += fabsf(n.x - q1);
    a2 += fabsf(n.x - q2); a3 += fabsf(n.x - q3);
    a0 += fabsf(n.y - q0); a1 += fabsf(n.y - q1);
    a2 += fabsf(n.y - q2); a3 += fabsf(n.y - q3);
    a0 += fabsf(n.z - q0); a1 += fabsf(n.z - q1);
    a2 += fabsf(n.z - q2); a3 += fabsf(n.z - q3);
    a0 += fabsf(n.w - q0); a1 += fabsf(n.w - q1);
    a2 += fabsf(n.w - q2); a3 += fabsf(n.w - q3);
  }

  float a = (a0 + a1) + (a2 + a3);
#pragma unroll
  for (int m = 32; m >= 1; m >>= 1) a += __shfl_xor(a, m, 64);
  __shared__ float wsum[4];
  if ((tid & 63) == 0) wsum[tid >> 6] = a;
  __syncthreads();
  if (tid == 0) atomicAdd(acc, (wsum[0] + wsum[1]) + (wsum[2] + wsum[3]));
}

// -------- kernel 3: closed-form S + final combine (single thread) ------------
__global__ void finalize_kernel(const float* __restrict__ acc,
                                float* __restrict__ out) {
  if (threadIdx.x == 0) {
    const double A  = (double)acc[0];
    const double Sp = (double)acc[1];
    const double Sn = (double)acc[2];
    // S = sum_{i,j} (MARGIN - p_i + n_j)
    const double S = (double)NNEG * ((double)NPOS * (double)MARGIN - Sp) +
                     (double)NPOS * Sn;
    const double loss = 0.5 * (S + A) / ((double)NPOS * (double)NNEG);
    out[0] = (float)loss;  // LAMBDA_STRUCT = 1.0
  }
}

extern "C" void kernel_launch(void* const* d_in, const int* in_sizes, int n_in,
                              void* d_out, int out_size, void* d_ws, size_t ws_size,
                              hipStream_t stream) {
  const float* emb = (const float*)d_in[0];
  const int* pos_idx = (const int*)d_in[1];
  const int* neg_idx = (const int*)d_in[2];
  float* out = (float*)d_out;

  float* wsf = (float*)d_ws;
  float* acc = wsf;        // 3 float accumulators
  float* sims = wsf + 64;  // 49152 floats of sims (pos then neg)

  hipMemsetAsync(acc, 0, 3 * sizeof(float), stream);

  // kernel 1: 49152 edges, one wave each, 4 waves/block
  sims_kernel<<<NEDGE / 4, 256, 0, stream>>>(emb, pos_idx, neg_idx, sims, acc);

  // kernel 2: 8 pos-chunks x 80 neg-segments
  pair_kernel<<<(NPOS / POSC) * (NNEG / NEGSEG), 256, 0, stream>>>(sims, acc);

  // kernel 3: trivial combine
  finalize_kernel<<<1, 64, 0, stream>>>(acc, out);
}

// Round 3
// 48.772 us; speedup vs baseline: 4.0486x; 4.0486x over previous
//
#include <hip/hip_runtime.h>

#define NPOS 8192
#define NNEG 40960
#define NEDGE (NPOS + NNEG)
#define DIM 128
#define MARGIN 0.1f

// acc[0] = A = sum_{i,j} |n_j - (p_i - M)|,  acc[1] = sum pos_sim,  acc[2] = sum neg_sim

// -------- kernel 1: one wave (64 lanes) per edge, dot product of two rows ----
// No atomics here (12K same-address atomics cost 160us in R2).
__global__ __launch_bounds__(256) void sims_kernel(
    const float* __restrict__ emb,
    const int* __restrict__ pos_idx,
    const int* __restrict__ neg_idx,
    float* __restrict__ sims) {
  const int tid = threadIdx.x;
  const int wave = blockIdx.x * 4 + (tid >> 6);
  const int lane = tid & 63;
  int s, d;
  if (wave < NPOS) {
    s = pos_idx[wave];
    d = pos_idx[NPOS + wave];
  } else {
    const int e = wave - NPOS;
    s = neg_idx[e];
    d = neg_idx[NNEG + e];
  }
  const float2 a = *(const float2*)(emb + (long long)s * DIM + lane * 2);
  const float2 b = *(const float2*)(emb + (long long)d * DIM + lane * 2);
  float v = a.x * b.x + a.y * b.y;
#pragma unroll
  for (int m = 32; m >= 1; m >>= 1) v += __shfl_xor(v, m, 64);
  if (lane == 0) sims[wave] = v;
}

// -------- kernel 2: A = sum |n_j - (p_i - M)|, plus Sp/Sn side-reductions ----
// grid = 8 pos-chunks (1024 each) x 80 neg-segments (512 each) = 640 blocks
#define POSC 1024
#define NEGSEG 512

__global__ __launch_bounds__(256) void pair_kernel(
    const float* __restrict__ sims, float* __restrict__ acc) {
  __shared__ float sneg[NEGSEG];
  const float* pos = sims;
  const float* neg = sims + NPOS;
  const int pc = blockIdx.x & 7;   // pos chunk
  const int ns = blockIdx.x >> 3;  // neg segment
  const int tid = threadIdx.x;

  for (int t = tid; t < NEGSEG; t += 256) sneg[t] = neg[ns * NEGSEG + t];

  const int pb = pc * POSC + tid;
  const float q0 = pos[pb]       - MARGIN;
  const float q1 = pos[pb + 256] - MARGIN;
  const float q2 = pos[pb + 512] - MARGIN;
  const float q3 = pos[pb + 768] - MARGIN;
  __syncthreads();

  float a0 = 0.f, a1 = 0.f, a2 = 0.f, a3 = 0.f;
#pragma unroll 4
  for (int j = 0; j < NEGSEG; j += 4) {
    const float4 n = *(const float4*)(sneg + j);
    a0 += fabsf(n.x - q0); a1 += fabsf(n.x - q1);
    a2 += fabsf(n.x - q2); a3 += fabsf(n.x - q3);
    a0 += fabsf(n.y - q0); a1 += fabsf(n.y - q1);
    a2 += fabsf(n.y - q2); a3 += fabsf(n.y - q3);
    a0 += fabsf(n.z - q0); a1 += fabsf(n.z - q1);
    a2 += fabsf(n.z - q2); a3 += fabsf(n.z - q3);
    a0 += fabsf(n.w - q0); a1 += fabsf(n.w - q1);
    a2 += fabsf(n.w - q2); a3 += fabsf(n.w - q3);
  }

  float a = (a0 + a1) + (a2 + a3);
  // Side reductions (negligible extra work, only ~90 extra atomics total):
  //   ns==0 blocks: sum of q over their pos chunk -> Sp = sum_q + POSC*MARGIN
  //   pc==0 blocks: sum of their neg segment      -> Sn
  float e1 = (ns == 0) ? ((q0 + q1) + (q2 + q3)) : 0.f;
  float e2 = (pc == 0) ? (sneg[tid] + sneg[tid + 256]) : 0.f;
#pragma unroll
  for (int m = 32; m >= 1; m >>= 1) {
    a  += __shfl_xor(a, m, 64);
    e1 += __shfl_xor(e1, m, 64);
    e2 += __shfl_xor(e2, m, 64);
  }
  __shared__ float wa[4], w1[4], w2[4];
  if ((tid & 63) == 0) {
    wa[tid >> 6] = a; w1[tid >> 6] = e1; w2[tid >> 6] = e2;
  }
  __syncthreads();
  if (tid == 0) {
    atomicAdd(acc, (wa[0] + wa[1]) + (wa[2] + wa[3]));
    if (ns == 0)
      atomicAdd(acc + 1,
                (w1[0] + w1[1]) + (w1[2] + w1[3]) + (float)POSC * MARGIN);
    if (pc == 0)
      atomicAdd(acc + 2, (w2[0] + w2[1]) + (w2[2] + w2[3]));
  }
}

// -------- kernel 3: closed-form S + final combine (single thread) ------------
__global__ void finalize_kernel(const float* __restrict__ acc,
                                float* __restrict__ out) {
  if (threadIdx.x == 0) {
    const double A  = (double)acc[0];
    const double Sp = (double)acc[1];
    const double Sn = (double)acc[2];
    // S = sum_{i,j} (MARGIN - p_i + n_j)
    const double S = (double)NNEG * ((double)NPOS * (double)MARGIN - Sp) +
                     (double)NPOS * Sn;
    const double loss = 0.5 * (S + A) / ((double)NPOS * (double)NNEG);
    out[0] = (float)loss;  // LAMBDA_STRUCT = 1.0
  }
}

extern "C" void kernel_launch(void* const* d_in, const int* in_sizes, int n_in,
                              void* d_out, int out_size, void* d_ws, size_t ws_size,
                              hipStream_t stream) {
  const float* emb = (const float*)d_in[0];
  const int* pos_idx = (const int*)d_in[1];
  const int* neg_idx = (const int*)d_in[2];
  float* out = (float*)d_out;

  float* wsf = (float*)d_ws;
  float* acc = wsf;        // 3 float accumulators
  float* sims = wsf + 64;  // 49152 floats of sims (pos then neg)

  hipMemsetAsync(acc, 0, 3 * sizeof(float), stream);

  // kernel 1: 49152 edges, one wave each, 4 waves/block
  sims_kernel<<<NEDGE / 4, 256, 0, stream>>>(emb, pos_idx, neg_idx, sims);

  // kernel 2: 8 pos-chunks x 80 neg-segments
  pair_kernel<<<(NPOS / POSC) * (NNEG / NEGSEG), 256, 0, stream>>>(sims, acc);

  // kernel 3: trivial combine
  finalize_kernel<<<1, 64, 0, stream>>>(acc, out);
}

// Round 4
// 43.587 us; speedup vs baseline: 4.5302x; 1.1189x over previous
//
#include <hip/hip_runtime.h>

#define NPOS 8192
#define NNEG 40960
#define NEDGE (NPOS + NNEG)
#define DIM 128
#define MARGIN 0.1f

// acc[0] = A = sum_{i,j} |n_j - (p_i - M)|,  acc[1] = sum pos_sim,  acc[2] = sum neg_sim

// -------- kernel 1: one wave (64 lanes) per edge, dot product of two rows ----
// Block 0 thread 0 zeroes the accumulators (hipMemsetAsync cost 41us/replay in
// R3; 12K same-address atomics cost 160us in R2 -- this does neither).
__global__ __launch_bounds__(256) void sims_kernel(
    const float* __restrict__ emb,
    const int* __restrict__ pos_idx,
    const int* __restrict__ neg_idx,
    float* __restrict__ sims, float* __restrict__ acc) {
  if (blockIdx.x == 0 && threadIdx.x == 0) {
    acc[0] = 0.f; acc[1] = 0.f; acc[2] = 0.f;
  }
  const int tid = threadIdx.x;
  const int wave = blockIdx.x * 4 + (tid >> 6);
  const int lane = tid & 63;
  int s, d;
  if (wave < NPOS) {
    s = pos_idx[wave];
    d = pos_idx[NPOS + wave];
  } else {
    const int e = wave - NPOS;
    s = neg_idx[e];
    d = neg_idx[NNEG + e];
  }
  const float2 a = *(const float2*)(emb + (long long)s * DIM + lane * 2);
  const float2 b = *(const float2*)(emb + (long long)d * DIM + lane * 2);
  float v = a.x * b.x + a.y * b.y;
#pragma unroll
  for (int m = 32; m >= 1; m >>= 1) v += __shfl_xor(v, m, 64);
  if (lane == 0) sims[wave] = v;
}

// -------- kernel 2: A = sum |n_j - (p_i - M)|, plus Sp/Sn side-reductions ----
// grid = 8 pos-chunks (1024 each) x 80 neg-segments (512 each) = 640 blocks
#define POSC 1024
#define NEGSEG 512

__global__ __launch_bounds__(256) void pair_kernel(
    const float* __restrict__ sims, float* __restrict__ acc) {
  __shared__ float sneg[NEGSEG];
  const float* pos = sims;
  const float* neg = sims + NPOS;
  const int pc = blockIdx.x & 7;   // pos chunk
  const int ns = blockIdx.x >> 3;  // neg segment
  const int tid = threadIdx.x;

  for (int t = tid; t < NEGSEG; t += 256) sneg[t] = neg[ns * NEGSEG + t];

  const int pb = pc * POSC + tid;
  const float q0 = pos[pb]       - MARGIN;
  const float q1 = pos[pb + 256] - MARGIN;
  const float q2 = pos[pb + 512] - MARGIN;
  const float q3 = pos[pb + 768] - MARGIN;
  __syncthreads();

  float a0 = 0.f, a1 = 0.f, a2 = 0.f, a3 = 0.f;
#pragma unroll 4
  for (int j = 0; j < NEGSEG; j += 4) {
    const float4 n = *(const float4*)(sneg + j);
    a0 += fabsf(n.x - q0); a1 += fabsf(n.x - q1);
    a2 += fabsf(n.x - q2); a3 += fabsf(n.x - q3);
    a0 += fabsf(n.y - q0); a1 += fabsf(n.y - q1);
    a2 += fabsf(n.y - q2); a3 += fabsf(n.y - q3);
    a0 += fabsf(n.z - q0); a1 += fabsf(n.z - q1);
    a2 += fabsf(n.z - q2); a3 += fabsf(n.z - q3);
    a0 += fabsf(n.w - q0); a1 += fabsf(n.w - q1);
    a2 += fabsf(n.w - q2); a3 += fabsf(n.w - q3);
  }

  float a = (a0 + a1) + (a2 + a3);
  // Side reductions:
  //   ns==0 blocks: sum of q over their pos chunk -> Sp = sum_q + POSC*MARGIN
  //   pc==0 blocks: sum of their neg segment      -> Sn
  float e1 = (ns == 0) ? ((q0 + q1) + (q2 + q3)) : 0.f;
  float e2 = (pc == 0) ? (sneg[tid] + sneg[tid + 256]) : 0.f;
#pragma unroll
  for (int m = 32; m >= 1; m >>= 1) {
    a  += __shfl_xor(a, m, 64);
    e1 += __shfl_xor(e1, m, 64);
    e2 += __shfl_xor(e2, m, 64);
  }
  __shared__ float wa[4], w1[4], w2[4];
  if ((tid & 63) == 0) {
    wa[tid >> 6] = a; w1[tid >> 6] = e1; w2[tid >> 6] = e2;
  }
  __syncthreads();
  if (tid == 0) {
    atomicAdd(acc, (wa[0] + wa[1]) + (wa[2] + wa[3]));
    if (ns == 0)
      atomicAdd(acc + 1,
                (w1[0] + w1[1]) + (w1[2] + w1[3]) + (float)POSC * MARGIN);
    if (pc == 0)
      atomicAdd(acc + 2, (w2[0] + w2[1]) + (w2[2] + w2[3]));
  }
}

// -------- kernel 3: closed-form S + final combine (single thread) ------------
__global__ void finalize_kernel(const float* __restrict__ acc,
                                float* __restrict__ out) {
  if (threadIdx.x == 0) {
    const double A  = (double)acc[0];
    const double Sp = (double)acc[1];
    const double Sn = (double)acc[2];
    // S = sum_{i,j} (MARGIN - p_i + n_j)
    const double S = (double)NNEG * ((double)NPOS * (double)MARGIN - Sp) +
                     (double)NPOS * Sn;
    const double loss = 0.5 * (S + A) / ((double)NPOS * (double)NNEG);
    out[0] = (float)loss;  // LAMBDA_STRUCT = 1.0
  }
}

extern "C" void kernel_launch(void* const* d_in, const int* in_sizes, int n_in,
                              void* d_out, int out_size, void* d_ws, size_t ws_size,
                              hipStream_t stream) {
  const float* emb = (const float*)d_in[0];
  const int* pos_idx = (const int*)d_in[1];
  const int* neg_idx = (const int*)d_in[2];
  float* out = (float*)d_out;

  float* wsf = (float*)d_ws;
  float* acc = wsf;        // 3 float accumulators
  float* sims = wsf + 64;  // 49152 floats of sims (pos then neg)

  // kernel 1: 49152 edges, one wave each, 4 waves/block (also zeroes acc)
  sims_kernel<<<NEDGE / 4, 256, 0, stream>>>(emb, pos_idx, neg_idx, sims, acc);

  // kernel 2: 8 pos-chunks x 80 neg-segments
  pair_kernel<<<(NPOS / POSC) * (NNEG / NEGSEG), 256, 0, stream>>>(sims, acc);

  // kernel 3: trivial combine
  finalize_kernel<<<1, 64, 0, stream>>>(acc, out);
}